// Round 21
// baseline (82.956 us; speedup 1.0000x reference)
//
#include <hip/hip_runtime.h>

#define NQ   65536
#define NC   4096
#define SOUT 64
#define NR   4                 // monomials (DEGREE=1, NDIM=3)
#define KTOT (NC + 64)         // 4160: k padded (chunk 64 = poly frags)
#define BM   64                // 2 q-groups x 32 q-rows per block
#define NCH  (NC / 64)         // 64 r2 chunks of BK=64
#define BP_BLOCKS 130
#define YE_BLOCKS 17

typedef float    f32x4 __attribute__((ext_vector_type(4)));
typedef _Float16 f16x8 __attribute__((ext_vector_type(8)));
typedef __fp16   h16x2 __attribute__((ext_vector_type(2)));
typedef unsigned uint4v __attribute__((ext_vector_type(4)));

// ---------------- single fused pre-kernel (writes d_ws; deterministic) -------
__global__ void prep_all(const float* __restrict__ coeffs,
                         const float* __restrict__ y,
                         _Float16* __restrict__ bp,
                         _Float16* __restrict__ ye) {
    if (blockIdx.x < BP_BLOCKS) {
        const int idx = blockIdx.x * 256 + threadIdx.x;
        if (idx >= 65 * 4 * 2 * 64) return;
        const int l  = idx & 63;
        const int kk = (idx >> 6) & 1;
        const int nf = (idx >> 7) & 3;
        const int ch = idx >> 9;
        const int n  = nf * 16 + (l & 15);
        const int ks = ch * 64 + kk * 32 + (l >> 4) * 8;
        f16x8 v;
        #pragma unroll
        for (int j = 0; j < 8; ++j) {
            const int k = ks + j;
            float f = 0.0f;
            if (k < NC)           f = coeffs[(size_t)k * SOUT + n] * 0.34657359f;
            else if (k < NC + NR) f = coeffs[(size_t)k * SOUT + n];
            v[j] = (_Float16)f;
        }
        *(f16x8*)(bp + (size_t)idx * 8) = v;
    } else {
        const int k = (blockIdx.x - BP_BLOCKS) * 256 + threadIdx.x;
        if (k >= KTOT) return;
        f16x8 r = {};
        if (k < NC) {
            const float a = y[k * 3 + 0], b = y[k * 3 + 1], c = y[k * 3 + 2];
            r[0] = (_Float16)(-2.0f * a); r[1] = (_Float16)(-2.0f * b);
            r[2] = (_Float16)(-2.0f * c); r[3] = (_Float16)1.0f;
            r[4] = (_Float16)(a * a + b * b + c * c + 0.02f);
        }
        *(f16x8*)(ye + (size_t)k * 8) = r;
    }
}

// ---------------- main kernel ------------------------------------------------
// Round-20 math, chunk-level COMPUTE pipeline: iteration i issues the 16
// out-MFMAs of chunk i-1 (fragments afp/Bp, fully data-independent of chunk
// i's loads and VALU log-chain) between chunk i's loads and chunk i's
// fragment computation -> matrix pipe and VALU/trans pipe can interleave.
// Accumulation order over chunks unchanged -> bit-identical results.
__launch_bounds__(256)
__global__ void rbf_mfma19(const float* __restrict__ x,
                           const _Float16* __restrict__ ye,
                           const float* __restrict__ shift,
                           const float* __restrict__ scale,
                           const _Float16* __restrict__ bp,
                           float* __restrict__ out) {
    __shared__ float red[2][32 * 64];   // 16 KB: [qg][elem][lane]

    const int t    = threadIdx.x;
    const int wave = t >> 6;
    const int lane = t & 63;
    const int l15  = lane & 15;
    const int lg   = lane >> 4;
    const int qg   = wave & 1;
    const int kh   = wave >> 1;
    const int qb   = blockIdx.x * BM + qg * 32;
    const int s    = kh * 32;

    // Xe B-fragments per q-half: lg==0 lanes hold [x0,x1,x2,xsq,1,0,0,0]
    f16x8 xef[2];
    uint2  poly01[2];
    #pragma unroll
    for (int qh = 0; qh < 2; ++qh) {
        const int q = qb + qh * 16 + l15;
        const float a = x[q * 3 + 0], b = x[q * 3 + 1], c = x[q * 3 + 2];
        f16x8 v = {};
        if (lg == 0) {
            v[0] = (_Float16)a; v[1] = (_Float16)b; v[2] = (_Float16)c;
            v[3] = (_Float16)(a * a + b * b + c * c); v[4] = (_Float16)1.0f;
        }
        xef[qh] = v;
        h16x2 p0 = __builtin_amdgcn_cvt_pkrtz(1.0f, (a - shift[0]) / scale[0]);
        h16x2 p1 = __builtin_amdgcn_cvt_pkrtz((b - shift[1]) / scale[1],
                                              (c - shift[2]) / scale[2]);
        poly01[qh].x = __builtin_bit_cast(unsigned, p0);
        poly01[qh].y = __builtin_bit_cast(unsigned, p1);
    }

    // running per-lane pointers (advance once per chunk; imm offsets inside)
    const _Float16* yp = ye + ((size_t)((l15 >> 2) * 8 + (l15 & 3))) * 8
                            + (size_t)s * 512;
    const _Float16* b0 = bp + (size_t)lane * 8 + (size_t)s * 4096;  // nf0/1
    const _Float16* b2 = b0 + 2048;                                 // nf2/3
    const _Float16* bpl = bp + (size_t)lane * 8;                    // poly tail

    f32x4 acc[2][4] = {};   // [qh][nf]
    f16x8 afp[2][2];        // prev-chunk A-frags [qh][kk]
    f16x8 Bp[4][2];         // prev-chunk B-frags [nf][kk]

#define LOADC(Y, Bc)                                                          \
    do {                                                                      \
        Y[0] = *(const f16x8*)(yp + 0);    Y[1] = *(const f16x8*)(yp + 256);  \
        Y[2] = *(const f16x8*)(yp + 32);   Y[3] = *(const f16x8*)(yp + 288);  \
        Bc[0][0] = *(const f16x8*)(b0 + 0);                                   \
        Bc[0][1] = *(const f16x8*)(b0 + 512);                                 \
        Bc[1][0] = *(const f16x8*)(b0 + 1024);                                \
        Bc[1][1] = *(const f16x8*)(b0 + 1536);                                \
        Bc[2][0] = *(const f16x8*)(b2 + 0);                                   \
        Bc[2][1] = *(const f16x8*)(b2 + 512);                                 \
        Bc[3][0] = *(const f16x8*)(b2 + 1024);                                \
        Bc[3][1] = *(const f16x8*)(b2 + 1536);                                \
        yp += 512; b0 += 4096; b2 += 4096;                                    \
    } while (0)

#define FRAGS(Y, af)                                                          \
    do {                                                                      \
        _Pragma("unroll")                                                     \
        for (int qh = 0; qh < 2; ++qh) {                                      \
            uint2 w[4];                                                       \
            _Pragma("unroll")                                                 \
            for (int kt = 0; kt < 4; ++kt) {                                  \
                f32x4 z = {};                                                 \
                const f32x4 r2 = __builtin_amdgcn_mfma_f32_16x16x32_f16(      \
                    Y[kt], xef[qh], z, 0, 0, 0);                              \
                float f[4];                                                   \
                _Pragma("unroll")                                             \
                for (int r = 0; r < 4; ++r)                                   \
                    f[r] = r2[r] * __log2f(__builtin_fabsf(r2[r]));           \
                h16x2 h0 = __builtin_amdgcn_cvt_pkrtz(f[0], f[1]);            \
                h16x2 h1 = __builtin_amdgcn_cvt_pkrtz(f[2], f[3]);            \
                w[kt].x = __builtin_bit_cast(unsigned, h0);                   \
                w[kt].y = __builtin_bit_cast(unsigned, h1);                   \
            }                                                                 \
            const uint4v a0 = {w[0].x, w[0].y, w[2].x, w[2].y};               \
            const uint4v a1 = {w[1].x, w[1].y, w[3].x, w[3].y};               \
            af[qh][0] = __builtin_bit_cast(f16x8, a0);                        \
            af[qh][1] = __builtin_bit_cast(f16x8, a1);                        \
        }                                                                     \
    } while (0)

#define OUTM(af, Bq)                                                          \
    do {                                                                      \
        _Pragma("unroll")                                                     \
        for (int qh = 0; qh < 2; ++qh)                                        \
            _Pragma("unroll")                                                 \
            for (int nf = 0; nf < 4; ++nf) {                                  \
                acc[qh][nf] = __builtin_amdgcn_mfma_f32_16x16x32_f16(         \
                    af[qh][0], Bq[nf][0], acc[qh][nf], 0, 0, 0);              \
                acc[qh][nf] = __builtin_amdgcn_mfma_f32_16x16x32_f16(         \
                    af[qh][1], Bq[nf][1], acc[qh][nf], 0, 0, 0);              \
            }                                                                 \
    } while (0)

    {   // prologue: chunk s
        f16x8 Y[4], Bc[4][2];
        LOADC(Y, Bc);
        FRAGS(Y, afp);
        #pragma unroll
        for (int nf = 0; nf < 4; ++nf) {
            Bp[nf][0] = Bc[nf][0]; Bp[nf][1] = Bc[nf][1];
        }
    }
    for (int ch = 1; ch < 32; ++ch) {
        f16x8 Y[4], Bc[4][2];
        LOADC(Y, Bc);          // loads for chunk ch (in flight during MFMAs)
        OUTM(afp, Bp);         // out-GEMM for chunk ch-1 (independent)
        FRAGS(Y, afp);         // VALU head for chunk ch (interleavable above)
        #pragma unroll
        for (int nf = 0; nf < 4; ++nf) {
            Bp[nf][0] = Bc[nf][0]; Bp[nf][1] = Bc[nf][1];
        }
    }
    OUTM(afp, Bp);             // drain: chunk s+31

#undef LOADC
#undef FRAGS
#undef OUTM

    if (kh == 1) {
        // ---- poly tail: chunk 64, kk=0 frags; A = [1,xh0,xh1,xh2,0...] ----
        #pragma unroll
        for (int qh = 0; qh < 2; ++qh) {
            uint4v ap = {};
            if (lg == 0) { ap.x = poly01[qh].x; ap.y = poly01[qh].y; }
            const f16x8 afq = __builtin_bit_cast(f16x8, ap);
            #pragma unroll
            for (int nf = 0; nf < 4; ++nf) {
                const f16x8 bpf = *(const f16x8*)(
                    bpl + ((size_t)((NCH * 4 + nf) * 2) << 9));
                acc[qh][nf] = __builtin_amdgcn_mfma_f32_16x16x32_f16(
                    afq, bpf, acc[qh][nf], 0, 0, 0);
            }
        }
        #pragma unroll
        for (int qh = 0; qh < 2; ++qh)
            #pragma unroll
            for (int nf = 0; nf < 4; ++nf)
                #pragma unroll
                for (int r = 0; r < 4; ++r)
                    red[qg][(qh * 16 + nf * 4 + r) * 64 + lane] = acc[qh][nf][r];
    }
    __syncthreads();
    if (kh == 0) {
        #pragma unroll
        for (int qh = 0; qh < 2; ++qh)
            #pragma unroll
            for (int nf = 0; nf < 4; ++nf)
                #pragma unroll
                for (int r = 0; r < 4; ++r)
                    acc[qh][nf][r] += red[qg][(qh * 16 + nf * 4 + r) * 64 + lane];

        // epilogue: C/D col=lane&15 (n), row=lg*4+r (q)
        #pragma unroll
        for (int qh = 0; qh < 2; ++qh)
            #pragma unroll
            for (int nf = 0; nf < 4; ++nf)
                #pragma unroll
                for (int r = 0; r < 4; ++r)
                    out[(size_t)(qb + qh * 16 + lg * 4 + r) * SOUT + nf * 16 + l15] =
                        acc[qh][nf][r];
    }
}

// ---------------- fallback (round-1 kernel) if d_ws too small ----------------
__launch_bounds__(256)
__global__ void rbf_tps_fallback(const float* __restrict__ x,
                                 const float* __restrict__ y,
                                 const float* __restrict__ coeffs,
                                 const float* __restrict__ shift,
                                 const float* __restrict__ scale,
                                 float* __restrict__ out) {
    __shared__ float4 ytile[NC];
    const int tid = threadIdx.x;
    for (int j = tid; j < NC; j += 256) {
        const float a = y[j * 3], b = y[j * 3 + 1], c = y[j * 3 + 2];
        ytile[j] = make_float4(a, b, c, a * a + b * b + c * c);
    }
    __syncthreads();
    const int q = blockIdx.x * 256 + tid;
    const float x0 = x[q * 3], x1 = x[q * 3 + 1], x2 = x[q * 3 + 2];
    const float xsq = x0 * x0 + x1 * x1 + x2 * x2;
    const float xh0 = (x0 - shift[0]) / scale[0];
    const float xh1 = (x1 - shift[1]) / scale[1];
    const float xh2 = (x2 - shift[2]) / scale[2];
    float acc[SOUT];
    {
        const float* c0 = &coeffs[(size_t)(NC + 0) * SOUT];
        const float* c1 = &coeffs[(size_t)(NC + 1) * SOUT];
        const float* c2 = &coeffs[(size_t)(NC + 2) * SOUT];
        const float* c3 = &coeffs[(size_t)(NC + 3) * SOUT];
        #pragma unroll
        for (int s = 0; s < SOUT; ++s)
            acc[s] = c0[s] + xh0 * c1[s] + xh1 * c2[s] + xh2 * c3[s];
    }
    #pragma unroll 2
    for (int j = 0; j < NC; ++j) {
        const float4 yj = ytile[j];
        const float dot = x0 * yj.x + x1 * yj.y + x2 * yj.z;
        float r2 = fmaf(-2.0f, dot, xsq + yj.w);
        r2 = fmaxf(r2, 0.0f);
        const float f = 0.5f * r2 * __logf(fmaxf(r2, 1e-37f));
        const float* __restrict__ cj = &coeffs[(size_t)j * SOUT];
        #pragma unroll
        for (int s = 0; s < SOUT; ++s) acc[s] = fmaf(f, cj[s], acc[s]);
    }
    float4* o4 = (float4*)&out[(size_t)q * SOUT];
    #pragma unroll
    for (int s = 0; s < SOUT / 4; ++s)
        o4[s] = make_float4(acc[4 * s], acc[4 * s + 1], acc[4 * s + 2], acc[4 * s + 3]);
}

extern "C" void kernel_launch(void* const* d_in, const int* in_sizes, int n_in,
                              void* d_out, int out_size, void* d_ws, size_t ws_size,
                              hipStream_t stream) {
    const float* x      = (const float*)d_in[0];
    const float* y      = (const float*)d_in[1];
    const float* coeffs = (const float*)d_in[2];
    const float* shift  = (const float*)d_in[3];
    const float* scale  = (const float*)d_in[4];
    float* out = (float*)d_out;

    const size_t bp_bytes = (size_t)65 * 4 * 2 * 64 * 8 * sizeof(_Float16); // 532,480
    const size_t ye_bytes = (size_t)KTOT * 8 * sizeof(_Float16);            //  66,560

    if (ws_size >= bp_bytes + ye_bytes) {
        _Float16* bpw = (_Float16*)d_ws;
        _Float16* yep = (_Float16*)((char*)d_ws + bp_bytes);
        hipLaunchKernelGGL(prep_all, dim3(BP_BLOCKS + YE_BLOCKS), dim3(256),
                           0, stream, coeffs, y, bpw, yep);
        hipLaunchKernelGGL(rbf_mfma19, dim3(NQ / BM), dim3(256), 0, stream,
                           x, yep, shift, scale, bpw, out);
    } else {
        hipLaunchKernelGGL(rbf_tps_fallback, dim3(NQ / 256), dim3(256),
                           0, stream, x, y, coeffs, shift, scale, out);
    }
}

// Round 23
// 75.537 us; speedup vs baseline: 1.0982x; 1.0982x over previous
//
#include <hip/hip_runtime.h>

#define NQ   65536
#define NC   4096
#define SOUT 64
#define NR   4                 // monomials (DEGREE=1, NDIM=3)
#define KTOT (NC + 64)         // 4160: k padded (chunk 64 = poly frags)
#define BM   64                // 2 q-groups x 32 q-rows per block
#define NCH  (NC / 64)         // 64 r2 chunks of BK=64
#define BP_BLOCKS 130
#define YE_BLOCKS 17

typedef float    f32x4 __attribute__((ext_vector_type(4)));
typedef _Float16 f16x8 __attribute__((ext_vector_type(8)));
typedef __fp16   h16x2 __attribute__((ext_vector_type(2)));
typedef unsigned uint4v __attribute__((ext_vector_type(4)));

// ---------------- single fused pre-kernel (writes d_ws; deterministic) -------
__global__ void prep_all(const float* __restrict__ coeffs,
                         const float* __restrict__ y,
                         _Float16* __restrict__ bp,
                         _Float16* __restrict__ ye) {
    if (blockIdx.x < BP_BLOCKS) {
        const int idx = blockIdx.x * 256 + threadIdx.x;
        if (idx >= 65 * 4 * 2 * 64) return;
        const int l  = idx & 63;
        const int kk = (idx >> 6) & 1;
        const int nf = (idx >> 7) & 3;
        const int ch = idx >> 9;
        const int n  = nf * 16 + (l & 15);
        const int ks = ch * 64 + kk * 32 + (l >> 4) * 8;
        f16x8 v;
        #pragma unroll
        for (int j = 0; j < 8; ++j) {
            const int k = ks + j;
            float f = 0.0f;
            if (k < NC)           f = coeffs[(size_t)k * SOUT + n] * 0.34657359f;
            else if (k < NC + NR) f = coeffs[(size_t)k * SOUT + n];
            v[j] = (_Float16)f;
        }
        *(f16x8*)(bp + (size_t)idx * 8) = v;
    } else {
        const int k = (blockIdx.x - BP_BLOCKS) * 256 + threadIdx.x;
        if (k >= KTOT) return;
        f16x8 r = {};
        if (k < NC) {
            const float a = y[k * 3 + 0], b = y[k * 3 + 1], c = y[k * 3 + 2];
            r[0] = (_Float16)(-2.0f * a); r[1] = (_Float16)(-2.0f * b);
            r[2] = (_Float16)(-2.0f * c); r[3] = (_Float16)1.0f;
            r[4] = (_Float16)(a * a + b * b + c * c + 0.02f);
        }
        *(f16x8*)(ye + (size_t)k * 8) = r;
    }
}

// ---------------- main kernel ------------------------------------------------
// Round-20 structure exactly (verified: 63.2 us kernel, absmax 4.0).
// f-eval: bit-hack log2 WITH safety clamp (round 22's failure = unguarded
// negative r2 from f16 cancellation noise, which can exceed the +0.02 bias
// when |x|,|y| are large; bitcast of a negative float -> log2 ~ -260 garbage).
//   rc = max(r2, 1e-8); log2(rc) ~= float(bitcast<int>(rc))*2^-23 - 126.94269504
// For clamped entries f = 1e-8*(-26.6) ~ 0 (matches exact-log behavior).
// Cost: 4 VALU ops/elem (max,cvt,fma,mul) vs log(16cy)+mul — removes the
// trans-pipe dominance (512 of ~630 VALU cy per chunk-wave).
__launch_bounds__(256, 4)
__global__ void rbf_mfma21(const float* __restrict__ x,
                           const _Float16* __restrict__ ye,
                           const float* __restrict__ shift,
                           const float* __restrict__ scale,
                           const _Float16* __restrict__ bp,
                           float* __restrict__ out) {
    __shared__ float red[2][32 * 64];   // 16 KB: [qg][elem][lane]

    const int t    = threadIdx.x;
    const int wave = t >> 6;
    const int lane = t & 63;
    const int l15  = lane & 15;
    const int lg   = lane >> 4;
    const int qg   = wave & 1;
    const int kh   = wave >> 1;
    const int qb   = blockIdx.x * BM + qg * 32;   // this wave's 32 q-rows
    const int s    = kh * 32;                     // first chunk of this k-half

    // Xe B-fragments per q-half: lg==0 lanes hold [x0,x1,x2,xsq,1,0,0,0]
    f16x8 xef[2];
    uint2  poly01[2];
    #pragma unroll
    for (int qh = 0; qh < 2; ++qh) {
        const int q = qb + qh * 16 + l15;
        const float a = x[q * 3 + 0], b = x[q * 3 + 1], c = x[q * 3 + 2];
        f16x8 v = {};
        if (lg == 0) {
            v[0] = (_Float16)a; v[1] = (_Float16)b; v[2] = (_Float16)c;
            v[3] = (_Float16)(a * a + b * b + c * c); v[4] = (_Float16)1.0f;
        }
        xef[qh] = v;
        h16x2 p0 = __builtin_amdgcn_cvt_pkrtz(1.0f, (a - shift[0]) / scale[0]);
        h16x2 p1 = __builtin_amdgcn_cvt_pkrtz((b - shift[1]) / scale[1],
                                              (c - shift[2]) / scale[2]);
        poly01[qh].x = __builtin_bit_cast(unsigned, p0);
        poly01[qh].y = __builtin_bit_cast(unsigned, p1);
    }

    // running per-lane pointers (advance once per chunk; imm offsets inside)
    const _Float16* yp = ye + ((size_t)((l15 >> 2) * 8 + (l15 & 3))) * 8
                            + (size_t)s * 512;
    const _Float16* b0 = bp + (size_t)lane * 8 + (size_t)s * 4096;  // nf0/1
    const _Float16* b2 = b0 + 2048;                                 // nf2/3
    const _Float16* bpl = bp + (size_t)lane * 8;                    // poly tail

    f32x4 acc[2][4] = {};   // [qh][nf]

    for (int ch = 0; ch < 32; ++ch) {
        // ---- Y rows (head of the r2 chain; issue first) ----
        f16x8 Y[4];
        Y[0] = *(const f16x8*)(yp + 0);
        Y[1] = *(const f16x8*)(yp + 256);
        Y[2] = *(const f16x8*)(yp + 32);
        Y[3] = *(const f16x8*)(yp + 288);

        // ---- B fragments: coalesced 1 KB bursts, imm offsets ----
        f16x8 B[4][2];
        B[0][0] = *(const f16x8*)(b0 + 0);
        B[0][1] = *(const f16x8*)(b0 + 512);
        B[1][0] = *(const f16x8*)(b0 + 1024);
        B[1][1] = *(const f16x8*)(b0 + 1536);
        B[2][0] = *(const f16x8*)(b2 + 0);
        B[2][1] = *(const f16x8*)(b2 + 512);
        B[3][0] = *(const f16x8*)(b2 + 1024);
        B[3][1] = *(const f16x8*)(b2 + 1536);

        yp += 512; b0 += 4096; b2 += 4096;

        // ---- per q-half: r2 tiles + f-eval + out-GEMM ----
        #pragma unroll
        for (int qh = 0; qh < 2; ++qh) {
            uint2 w[4];
            #pragma unroll
            for (int kt = 0; kt < 4; ++kt) {
                f32x4 z = {};
                const f32x4 r2 = __builtin_amdgcn_mfma_f32_16x16x32_f16(
                    Y[kt], xef[qh], z, 0, 0, 0);
                float f[4];
                #pragma unroll
                for (int r = 0; r < 4; ++r) {
                    const float rc = fmaxf(r2[r], 1e-8f);   // guard negatives
                    const float fi = (float)__builtin_bit_cast(int, rc);
                    f[r] = rc * fmaf(fi, 1.1920929e-7f, -126.94269504f);
                }
                h16x2 h0 = __builtin_amdgcn_cvt_pkrtz(f[0], f[1]);
                h16x2 h1 = __builtin_amdgcn_cvt_pkrtz(f[2], f[3]);
                w[kt].x = __builtin_bit_cast(unsigned, h0);
                w[kt].y = __builtin_bit_cast(unsigned, h1);
            }
            const uint4v a0 = {w[0].x, w[0].y, w[2].x, w[2].y};
            const uint4v a1 = {w[1].x, w[1].y, w[3].x, w[3].y};
            const f16x8 af0 = __builtin_bit_cast(f16x8, a0);
            const f16x8 af1 = __builtin_bit_cast(f16x8, a1);
            #pragma unroll
            for (int nf = 0; nf < 4; ++nf) {
                acc[qh][nf] = __builtin_amdgcn_mfma_f32_16x16x32_f16(
                    af0, B[nf][0], acc[qh][nf], 0, 0, 0);
                acc[qh][nf] = __builtin_amdgcn_mfma_f32_16x16x32_f16(
                    af1, B[nf][1], acc[qh][nf], 0, 0, 0);
            }
        }
    }

    if (kh == 1) {
        // ---- poly tail: chunk 64, kk=0 frags; A = [1,xh0,xh1,xh2,0...] ----
        #pragma unroll
        for (int qh = 0; qh < 2; ++qh) {
            uint4v ap = {};
            if (lg == 0) { ap.x = poly01[qh].x; ap.y = poly01[qh].y; }
            const f16x8 afp = __builtin_bit_cast(f16x8, ap);
            #pragma unroll
            for (int nf = 0; nf < 4; ++nf) {
                const f16x8 bpf = *(const f16x8*)(
                    bpl + ((size_t)((NCH * 4 + nf) * 2) << 9));
                acc[qh][nf] = __builtin_amdgcn_mfma_f32_16x16x32_f16(
                    afp, bpf, acc[qh][nf], 0, 0, 0);
            }
        }
        // write partials: [elem][lane] layout -> conflict-free b32 stores
        #pragma unroll
        for (int qh = 0; qh < 2; ++qh)
            #pragma unroll
            for (int nf = 0; nf < 4; ++nf)
                #pragma unroll
                for (int r = 0; r < 4; ++r)
                    red[qg][(qh * 16 + nf * 4 + r) * 64 + lane] = acc[qh][nf][r];
    }
    __syncthreads();
    if (kh == 0) {
        #pragma unroll
        for (int qh = 0; qh < 2; ++qh)
            #pragma unroll
            for (int nf = 0; nf < 4; ++nf)
                #pragma unroll
                for (int r = 0; r < 4; ++r)
                    acc[qh][nf][r] += red[qg][(qh * 16 + nf * 4 + r) * 64 + lane];

        // epilogue: C/D col=lane&15 (n), row=lg*4+r (q)
        #pragma unroll
        for (int qh = 0; qh < 2; ++qh)
            #pragma unroll
            for (int nf = 0; nf < 4; ++nf)
                #pragma unroll
                for (int r = 0; r < 4; ++r)
                    out[(size_t)(qb + qh * 16 + lg * 4 + r) * SOUT + nf * 16 + l15] =
                        acc[qh][nf][r];
    }
}

// ---------------- fallback (round-1 kernel) if d_ws too small ----------------
__launch_bounds__(256)
__global__ void rbf_tps_fallback(const float* __restrict__ x,
                                 const float* __restrict__ y,
                                 const float* __restrict__ coeffs,
                                 const float* __restrict__ shift,
                                 const float* __restrict__ scale,
                                 float* __restrict__ out) {
    __shared__ float4 ytile[NC];
    const int tid = threadIdx.x;
    for (int j = tid; j < NC; j += 256) {
        const float a = y[j * 3], b = y[j * 3 + 1], c = y[j * 3 + 2];
        ytile[j] = make_float4(a, b, c, a * a + b * b + c * c);
    }
    __syncthreads();
    const int q = blockIdx.x * 256 + tid;
    const float x0 = x[q * 3], x1 = x[q * 3 + 1], x2 = x[q * 3 + 2];
    const float xsq = x0 * x0 + x1 * x1 + x2 * x2;
    const float xh0 = (x0 - shift[0]) / scale[0];
    const float xh1 = (x1 - shift[1]) / scale[1];
    const float xh2 = (x2 - shift[2]) / scale[2];
    float acc[SOUT];
    {
        const float* c0 = &coeffs[(size_t)(NC + 0) * SOUT];
        const float* c1 = &coeffs[(size_t)(NC + 1) * SOUT];
        const float* c2 = &coeffs[(size_t)(NC + 2) * SOUT];
        const float* c3 = &coeffs[(size_t)(NC + 3) * SOUT];
        #pragma unroll
        for (int s = 0; s < SOUT; ++s)
            acc[s] = c0[s] + xh0 * c1[s] + xh1 * c2[s] + xh2 * c3[s];
    }
    #pragma unroll 2
    for (int j = 0; j < NC; ++j) {
        const float4 yj = ytile[j];
        const float dot = x0 * yj.x + x1 * yj.y + x2 * yj.z;
        float r2 = fmaf(-2.0f, dot, xsq + yj.w);
        r2 = fmaxf(r2, 0.0f);
        const float f = 0.5f * r2 * __logf(fmaxf(r2, 1e-37f));
        const float* __restrict__ cj = &coeffs[(size_t)j * SOUT];
        #pragma unroll
        for (int s = 0; s < SOUT; ++s) acc[s] = fmaf(f, cj[s], acc[s]);
    }
    float4* o4 = (float4*)&out[(size_t)q * SOUT];
    #pragma unroll
    for (int s = 0; s < SOUT / 4; ++s)
        o4[s] = make_float4(acc[4 * s], acc[4 * s + 1], acc[4 * s + 2], acc[4 * s + 3]);
}

extern "C" void kernel_launch(void* const* d_in, const int* in_sizes, int n_in,
                              void* d_out, int out_size, void* d_ws, size_t ws_size,
                              hipStream_t stream) {
    const float* x      = (const float*)d_in[0];
    const float* y      = (const float*)d_in[1];
    const float* coeffs = (const float*)d_in[2];
    const float* shift  = (const float*)d_in[3];
    const float* scale  = (const float*)d_in[4];
    float* out = (float*)d_out;

    const size_t bp_bytes = (size_t)65 * 4 * 2 * 64 * 8 * sizeof(_Float16); // 532,480
    const size_t ye_bytes = (size_t)KTOT * 8 * sizeof(_Float16);            //  66,560

    if (ws_size >= bp_bytes + ye_bytes) {
        _Float16* bpw = (_Float16*)d_ws;
        _Float16* yep = (_Float16*)((char*)d_ws + bp_bytes);
        hipLaunchKernelGGL(prep_all, dim3(BP_BLOCKS + YE_BLOCKS), dim3(256),
                           0, stream, coeffs, y, bpw, yep);
        hipLaunchKernelGGL(rbf_mfma21, dim3(NQ / BM), dim3(256), 0, stream,
                           x, yep, shift, scale, bpw, out);
    } else {
        hipLaunchKernelGGL(rbf_tps_fallback, dim3(NQ / 256), dim3(256),
                           0, stream, x, y, coeffs, shift, scale, out);
    }
}

// Round 24
// 67.173 us; speedup vs baseline: 1.2350x; 1.1245x over previous
//
#include <hip/hip_runtime.h>

#define NQ   65536
#define NC   4096
#define SOUT 64
#define NR   4                 // monomials (DEGREE=1, NDIM=3)
#define KTOT (NC + 64)         // 4160: k padded (chunk 64 = poly frags)
#define BM   64                // 2 q-groups x 32 q-rows per block
#define NCH  (NC / 64)         // 64 r2 chunks of BK=64
#define BP_BLOCKS 130
#define YE_BLOCKS 17

typedef float    f32x4 __attribute__((ext_vector_type(4)));
typedef _Float16 f16x8 __attribute__((ext_vector_type(8)));
typedef __fp16   h16x2 __attribute__((ext_vector_type(2)));
typedef unsigned uint4v __attribute__((ext_vector_type(4)));

// ---------------- single fused pre-kernel (writes d_ws; deterministic) -------
__global__ void prep_all(const float* __restrict__ coeffs,
                         const float* __restrict__ y,
                         _Float16* __restrict__ bp,
                         _Float16* __restrict__ ye) {
    if (blockIdx.x < BP_BLOCKS) {
        const int idx = blockIdx.x * 256 + threadIdx.x;
        if (idx >= 65 * 4 * 2 * 64) return;
        const int l  = idx & 63;
        const int kk = (idx >> 6) & 1;
        const int nf = (idx >> 7) & 3;
        const int ch = idx >> 9;
        const int n  = nf * 16 + (l & 15);
        const int ks = ch * 64 + kk * 32 + (l >> 4) * 8;
        f16x8 v;
        #pragma unroll
        for (int j = 0; j < 8; ++j) {
            const int k = ks + j;
            float f = 0.0f;
            if (k < NC)           f = coeffs[(size_t)k * SOUT + n] * 0.34657359f;
            else if (k < NC + NR) f = coeffs[(size_t)k * SOUT + n];
            v[j] = (_Float16)f;
        }
        *(f16x8*)(bp + (size_t)idx * 8) = v;
    } else {
        const int k = (blockIdx.x - BP_BLOCKS) * 256 + threadIdx.x;
        if (k >= KTOT) return;
        f16x8 r = {};
        if (k < NC) {
            const float a = y[k * 3 + 0], b = y[k * 3 + 1], c = y[k * 3 + 2];
            r[0] = (_Float16)(-2.0f * a); r[1] = (_Float16)(-2.0f * b);
            r[2] = (_Float16)(-2.0f * c); r[3] = (_Float16)1.0f;
            r[4] = (_Float16)(a * a + b * b + c * c + 0.02f);
        }
        *(f16x8*)(ye + (size_t)k * 8) = r;
    }
}

// ---------------- main kernel ------------------------------------------------
// Round-20 verified best (63.2 us kernel, absmax 4.0): 2-way K-split, plain
// C++ loads, register A-frag trick (kappa permutation makes r2-MFMA output =
// out-GEMM A-fragment layout, zero data movement), no clamp (ysq +0.02 bias,
// free |.| modifier on v_log), exact v_log_f32 (trans pipe — overlapped;
// round 23 proved the bit-hack log is SLOWER by loading the main VALU pipe),
// LDS [elem][lane] merge, fused prep, running pointers with imm offsets.
// Issue-bound at VALUBusy 53% + MfmaUtil 35% ~= 88% combined.
__launch_bounds__(256, 4)
__global__ void rbf_mfma22(const float* __restrict__ x,
                           const _Float16* __restrict__ ye,
                           const float* __restrict__ shift,
                           const float* __restrict__ scale,
                           const _Float16* __restrict__ bp,
                           float* __restrict__ out) {
    __shared__ float red[2][32 * 64];   // 16 KB: [qg][elem][lane]

    const int t    = threadIdx.x;
    const int wave = t >> 6;
    const int lane = t & 63;
    const int l15  = lane & 15;
    const int lg   = lane >> 4;
    const int qg   = wave & 1;
    const int kh   = wave >> 1;
    const int qb   = blockIdx.x * BM + qg * 32;   // this wave's 32 q-rows
    const int s    = kh * 32;                     // first chunk of this k-half

    // Xe B-fragments per q-half: lg==0 lanes hold [x0,x1,x2,xsq,1,0,0,0]
    f16x8 xef[2];
    uint2  poly01[2];
    #pragma unroll
    for (int qh = 0; qh < 2; ++qh) {
        const int q = qb + qh * 16 + l15;
        const float a = x[q * 3 + 0], b = x[q * 3 + 1], c = x[q * 3 + 2];
        f16x8 v = {};
        if (lg == 0) {
            v[0] = (_Float16)a; v[1] = (_Float16)b; v[2] = (_Float16)c;
            v[3] = (_Float16)(a * a + b * b + c * c); v[4] = (_Float16)1.0f;
        }
        xef[qh] = v;
        h16x2 p0 = __builtin_amdgcn_cvt_pkrtz(1.0f, (a - shift[0]) / scale[0]);
        h16x2 p1 = __builtin_amdgcn_cvt_pkrtz((b - shift[1]) / scale[1],
                                              (c - shift[2]) / scale[2]);
        poly01[qh].x = __builtin_bit_cast(unsigned, p0);
        poly01[qh].y = __builtin_bit_cast(unsigned, p1);
    }

    // running per-lane pointers (advance once per chunk; imm offsets inside)
    const _Float16* yp = ye + ((size_t)((l15 >> 2) * 8 + (l15 & 3))) * 8
                            + (size_t)s * 512;
    const _Float16* b0 = bp + (size_t)lane * 8 + (size_t)s * 4096;  // nf0/1
    const _Float16* b2 = b0 + 2048;                                 // nf2/3
    const _Float16* bpl = bp + (size_t)lane * 8;                    // poly tail

    f32x4 acc[2][4] = {};   // [qh][nf]

    for (int ch = 0; ch < 32; ++ch) {
        // ---- Y rows (head of the r2 chain; issue first) ----
        f16x8 Y[4];
        Y[0] = *(const f16x8*)(yp + 0);
        Y[1] = *(const f16x8*)(yp + 256);
        Y[2] = *(const f16x8*)(yp + 32);
        Y[3] = *(const f16x8*)(yp + 288);

        // ---- B fragments: coalesced 1 KB bursts, imm offsets ----
        f16x8 B[4][2];
        B[0][0] = *(const f16x8*)(b0 + 0);
        B[0][1] = *(const f16x8*)(b0 + 512);
        B[1][0] = *(const f16x8*)(b0 + 1024);
        B[1][1] = *(const f16x8*)(b0 + 1536);
        B[2][0] = *(const f16x8*)(b2 + 0);
        B[2][1] = *(const f16x8*)(b2 + 512);
        B[3][0] = *(const f16x8*)(b2 + 1024);
        B[3][1] = *(const f16x8*)(b2 + 1536);

        yp += 512; b0 += 4096; b2 += 4096;

        // ---- per q-half: r2 tiles + f-eval + out-GEMM ----
        #pragma unroll
        for (int qh = 0; qh < 2; ++qh) {
            uint2 w[4];
            #pragma unroll
            for (int kt = 0; kt < 4; ++kt) {
                f32x4 z = {};
                const f32x4 r2 = __builtin_amdgcn_mfma_f32_16x16x32_f16(
                    Y[kt], xef[qh], z, 0, 0, 0);
                float f[4];
                #pragma unroll
                for (int r = 0; r < 4; ++r) {
                    // r2 > 0 by ysq bias; |.| folds into v_log as input modifier
                    f[r] = r2[r] * __log2f(__builtin_fabsf(r2[r]));
                }
                h16x2 h0 = __builtin_amdgcn_cvt_pkrtz(f[0], f[1]);
                h16x2 h1 = __builtin_amdgcn_cvt_pkrtz(f[2], f[3]);
                w[kt].x = __builtin_bit_cast(unsigned, h0);
                w[kt].y = __builtin_bit_cast(unsigned, h1);
            }
            const uint4v a0 = {w[0].x, w[0].y, w[2].x, w[2].y};
            const uint4v a1 = {w[1].x, w[1].y, w[3].x, w[3].y};
            const f16x8 af0 = __builtin_bit_cast(f16x8, a0);
            const f16x8 af1 = __builtin_bit_cast(f16x8, a1);
            #pragma unroll
            for (int nf = 0; nf < 4; ++nf) {
                acc[qh][nf] = __builtin_amdgcn_mfma_f32_16x16x32_f16(
                    af0, B[nf][0], acc[qh][nf], 0, 0, 0);
                acc[qh][nf] = __builtin_amdgcn_mfma_f32_16x16x32_f16(
                    af1, B[nf][1], acc[qh][nf], 0, 0, 0);
            }
        }
    }

    if (kh == 1) {
        // ---- poly tail: chunk 64, kk=0 frags; A = [1,xh0,xh1,xh2,0...] ----
        #pragma unroll
        for (int qh = 0; qh < 2; ++qh) {
            uint4v ap = {};
            if (lg == 0) { ap.x = poly01[qh].x; ap.y = poly01[qh].y; }
            const f16x8 afp = __builtin_bit_cast(f16x8, ap);
            #pragma unroll
            for (int nf = 0; nf < 4; ++nf) {
                const f16x8 bpf = *(const f16x8*)(
                    bpl + ((size_t)((NCH * 4 + nf) * 2) << 9));
                acc[qh][nf] = __builtin_amdgcn_mfma_f32_16x16x32_f16(
                    afp, bpf, acc[qh][nf], 0, 0, 0);
            }
        }
        // write partials: [elem][lane] layout -> conflict-free b32 stores
        #pragma unroll
        for (int qh = 0; qh < 2; ++qh)
            #pragma unroll
            for (int nf = 0; nf < 4; ++nf)
                #pragma unroll
                for (int r = 0; r < 4; ++r)
                    red[qg][(qh * 16 + nf * 4 + r) * 64 + lane] = acc[qh][nf][r];
    }
    __syncthreads();
    if (kh == 0) {
        #pragma unroll
        for (int qh = 0; qh < 2; ++qh)
            #pragma unroll
            for (int nf = 0; nf < 4; ++nf)
                #pragma unroll
                for (int r = 0; r < 4; ++r)
                    acc[qh][nf][r] += red[qg][(qh * 16 + nf * 4 + r) * 64 + lane];

        // epilogue: C/D col=lane&15 (n), row=lg*4+r (q)
        #pragma unroll
        for (int qh = 0; qh < 2; ++qh)
            #pragma unroll
            for (int nf = 0; nf < 4; ++nf)
                #pragma unroll
                for (int r = 0; r < 4; ++r)
                    out[(size_t)(qb + qh * 16 + lg * 4 + r) * SOUT + nf * 16 + l15] =
                        acc[qh][nf][r];
    }
}

// ---------------- fallback (round-1 kernel) if d_ws too small ----------------
__launch_bounds__(256)
__global__ void rbf_tps_fallback(const float* __restrict__ x,
                                 const float* __restrict__ y,
                                 const float* __restrict__ coeffs,
                                 const float* __restrict__ shift,
                                 const float* __restrict__ scale,
                                 float* __restrict__ out) {
    __shared__ float4 ytile[NC];
    const int tid = threadIdx.x;
    for (int j = tid; j < NC; j += 256) {
        const float a = y[j * 3], b = y[j * 3 + 1], c = y[j * 3 + 2];
        ytile[j] = make_float4(a, b, c, a * a + b * b + c * c);
    }
    __syncthreads();
    const int q = blockIdx.x * 256 + tid;
    const float x0 = x[q * 3], x1 = x[q * 3 + 1], x2 = x[q * 3 + 2];
    const float xsq = x0 * x0 + x1 * x1 + x2 * x2;
    const float xh0 = (x0 - shift[0]) / scale[0];
    const float xh1 = (x1 - shift[1]) / scale[1];
    const float xh2 = (x2 - shift[2]) / scale[2];
    float acc[SOUT];
    {
        const float* c0 = &coeffs[(size_t)(NC + 0) * SOUT];
        const float* c1 = &coeffs[(size_t)(NC + 1) * SOUT];
        const float* c2 = &coeffs[(size_t)(NC + 2) * SOUT];
        const float* c3 = &coeffs[(size_t)(NC + 3) * SOUT];
        #pragma unroll
        for (int s = 0; s < SOUT; ++s)
            acc[s] = c0[s] + xh0 * c1[s] + xh1 * c2[s] + xh2 * c3[s];
    }
    #pragma unroll 2
    for (int j = 0; j < NC; ++j) {
        const float4 yj = ytile[j];
        const float dot = x0 * yj.x + x1 * yj.y + x2 * yj.z;
        float r2 = fmaf(-2.0f, dot, xsq + yj.w);
        r2 = fmaxf(r2, 0.0f);
        const float f = 0.5f * r2 * __logf(fmaxf(r2, 1e-37f));
        const float* __restrict__ cj = &coeffs[(size_t)j * SOUT];
        #pragma unroll
        for (int s = 0; s < SOUT; ++s) acc[s] = fmaf(f, cj[s], acc[s]);
    }
    float4* o4 = (float4*)&out[(size_t)q * SOUT];
    #pragma unroll
    for (int s = 0; s < SOUT / 4; ++s)
        o4[s] = make_float4(acc[4 * s], acc[4 * s + 1], acc[4 * s + 2], acc[4 * s + 3]);
}

extern "C" void kernel_launch(void* const* d_in, const int* in_sizes, int n_in,
                              void* d_out, int out_size, void* d_ws, size_t ws_size,
                              hipStream_t stream) {
    const float* x      = (const float*)d_in[0];
    const float* y      = (const float*)d_in[1];
    const float* coeffs = (const float*)d_in[2];
    const float* shift  = (const float*)d_in[3];
    const float* scale  = (const float*)d_in[4];
    float* out = (float*)d_out;

    const size_t bp_bytes = (size_t)65 * 4 * 2 * 64 * 8 * sizeof(_Float16); // 532,480
    const size_t ye_bytes = (size_t)KTOT * 8 * sizeof(_Float16);            //  66,560

    if (ws_size >= bp_bytes + ye_bytes) {
        _Float16* bpw = (_Float16*)d_ws;
        _Float16* yep = (_Float16*)((char*)d_ws + bp_bytes);
        hipLaunchKernelGGL(prep_all, dim3(BP_BLOCKS + YE_BLOCKS), dim3(256),
                           0, stream, coeffs, y, bpw, yep);
        hipLaunchKernelGGL(rbf_mfma22, dim3(NQ / BM), dim3(256), 0, stream,
                           x, yep, shift, scale, bpw, out);
    } else {
        hipLaunchKernelGGL(rbf_tps_fallback, dim3(NQ / 256), dim3(256),
                           0, stream, x, y, coeffs, shift, scale, out);
    }
}